// Round 5
// baseline (429.898 us; speedup 1.0000x reference)
//
#include <hip/hip_runtime.h>
#include <hip/hip_bf16.h>
#include <cstdint>
#include <cstddef>

#define S_LEN 2048
#define D_HEAD 64
#define NBH 32                      // B*H = 2*16
#define NELEM 4194304               // NBH * S_LEN * D_HEAD

typedef __attribute__((ext_vector_type(8))) short short8;
typedef __attribute__((ext_vector_type(4))) float f32x4;

__device__ __forceinline__ short f2bf(float f) {
    union { float f; uint32_t u; } v; v.f = f;
    uint32_t u = v.u + 0x7FFFu + ((v.u >> 16) & 1u);   // RNE, inputs finite
    return (short)(u >> 16);
}

__device__ __forceinline__ uint32_t pkbf(float lo, float hi) {
    return ((uint32_t)(uint16_t)f2bf(hi) << 16) | (uint32_t)(uint16_t)f2bf(lo);
}

// K fp32 -> bf16, same layout
__global__ void convert_k_kernel(const float* __restrict__ K, short* __restrict__ Kb) {
    int i = blockIdx.x * 256 + threadIdx.x;
    float4 x = reinterpret_cast<const float4*>(K)[i];
    short4 y;
    y.x = f2bf(x.x); y.y = f2bf(x.y); y.z = f2bf(x.z); y.w = f2bf(x.w);
    reinterpret_cast<short4*>(Kb)[i] = y;
}

// V fp32 [bh][S][D] -> bf16 transposed [bh][D][S]
__global__ void transpose_v_kernel(const float* __restrict__ V, short* __restrict__ Vtb) {
    __shared__ float tile[64][65];
    const int bh = blockIdx.y;
    const int s0 = blockIdx.x * 64;
    const int d = threadIdx.x & 63;
    const int r = threadIdx.x >> 6;
    const float* vp = V + ((size_t)bh * S_LEN + s0) * D_HEAD;
    #pragma unroll
    for (int i = 0; i < 16; ++i) {
        int s = i * 4 + r;
        tile[s][d] = vp[(size_t)s * D_HEAD + d];
    }
    __syncthreads();
    short* op = Vtb + (size_t)bh * (D_HEAD * S_LEN) + s0;
    #pragma unroll
    for (int i = 0; i < 16; ++i) {
        int dd = i * 4 + r;
        op[(size_t)dd * S_LEN + d] = f2bf(tile[d][dd]);
    }
}

// Kernel A: softmax denominator + PV + Out; writes rl = 1/l per q-row to Rl.
// Swapped QK^T: mfma(A=K, B=Q) -> lane holds scores for q = lane&15 at
// k = (lane>>4)*4 + reg (+16 for the c1 tile). PV A-frag built by in-register
// 4x4 word transpose across lane-groups via 8 ds_bpermute. No LDS, no fences.
__launch_bounds__(256, 4)
__global__ void attn_pv_kernel(const float* __restrict__ Q,
                               const short* __restrict__ Kb,
                               const short* __restrict__ Vtb,
                               float* __restrict__ Out,
                               float* __restrict__ Rl) {
    const int lane = threadIdx.x & 63;
    const int w    = threadIdx.x >> 6;
    const int bh   = blockIdx.y;
    const int qbase = blockIdx.x * 64 + w * 16;
    const int lrow = lane & 15;
    const int lgrp = lane >> 4;
    const float scale = 0.125f;                        // 1/sqrt(64)

    short8 q0, q1;
    {
        const float* qr = Q + ((size_t)bh * S_LEN + qbase + lrow) * D_HEAD + lgrp * 8;
        #pragma unroll
        for (int e = 0; e < 8; ++e) q0[e] = f2bf(qr[e]);
        #pragma unroll
        for (int e = 0; e < 8; ++e) q1[e] = f2bf(qr[e + 32]);
    }

    const short* Kp = Kb + (size_t)bh * (S_LEN * D_HEAD);
    const short* Vp = Vtb + (size_t)bh * (D_HEAD * S_LEN);

    // bpermute source lanes for the 4x4 word transpose (byte addr = lane*4)
    const int srcA = ((lane & 15) + ((lane >> 4) & 1) * 32) << 2;
    const int srcB = srcA + (16 << 2);
    const bool glow = (lgrp < 2);

    float l = 0.f;
    f32x4 acc[4] = {};
    for (int j0 = 0; j0 < S_LEN; j0 += 32) {
        const short* kr0 = Kp + (size_t)(j0 + lrow) * D_HEAD + lgrp * 8;
        const short* kr1 = kr0 + 16 * D_HEAD;
        short8 k00 = *reinterpret_cast<const short8*>(kr0);
        short8 k01 = *reinterpret_cast<const short8*>(kr0 + 32);
        short8 k10 = *reinterpret_cast<const short8*>(kr1);
        short8 k11 = *reinterpret_cast<const short8*>(kr1 + 32);
        short8 bv0 = *reinterpret_cast<const short8*>(Vp + (size_t)(0 * 16 + lrow) * S_LEN + j0 + lgrp * 8);
        short8 bv1 = *reinterpret_cast<const short8*>(Vp + (size_t)(1 * 16 + lrow) * S_LEN + j0 + lgrp * 8);
        short8 bv2 = *reinterpret_cast<const short8*>(Vp + (size_t)(2 * 16 + lrow) * S_LEN + j0 + lgrp * 8);
        short8 bv3 = *reinterpret_cast<const short8*>(Vp + (size_t)(3 * 16 + lrow) * S_LEN + j0 + lgrp * 8);
        f32x4 c0 = {0.f, 0.f, 0.f, 0.f};
        f32x4 c1 = {0.f, 0.f, 0.f, 0.f};
        c0 = __builtin_amdgcn_mfma_f32_16x16x32_bf16(k00, q0, c0, 0, 0, 0);
        c0 = __builtin_amdgcn_mfma_f32_16x16x32_bf16(k01, q1, c0, 0, 0, 0);
        c1 = __builtin_amdgcn_mfma_f32_16x16x32_bf16(k10, q0, c1, 0, 0, 0);
        c1 = __builtin_amdgcn_mfma_f32_16x16x32_bf16(k11, q1, c1, 0, 0, 0);

        float e0[4], e1[4];
        #pragma unroll
        for (int rr = 0; rr < 4; ++rr) {
            e0[rr] = __expf(c0[rr] * scale);
            e1[rr] = __expf(c1[rr] * scale);
            l += e0[rr] + e1[rr];
        }
        int w00 = (int)pkbf(e0[0], e0[1]);
        int w01 = (int)pkbf(e0[2], e0[3]);
        int w10 = (int)pkbf(e1[0], e1[1]);
        int w11 = (int)pkbf(e1[2], e1[3]);
        int t0 = __builtin_amdgcn_ds_bpermute(srcA, w00);
        int t1 = __builtin_amdgcn_ds_bpermute(srcA, w01);
        int t2 = __builtin_amdgcn_ds_bpermute(srcB, w00);
        int t3 = __builtin_amdgcn_ds_bpermute(srcB, w01);
        int u0 = __builtin_amdgcn_ds_bpermute(srcA, w10);
        int u1 = __builtin_amdgcn_ds_bpermute(srcA, w11);
        int u2 = __builtin_amdgcn_ds_bpermute(srcB, w10);
        int u3 = __builtin_amdgcn_ds_bpermute(srcB, w11);
        union { short8 s8; int wd[4]; } fr;
        fr.wd[0] = glow ? t0 : u0;
        fr.wd[1] = glow ? t1 : u1;
        fr.wd[2] = glow ? t2 : u2;
        fr.wd[3] = glow ? t3 : u3;

        acc[0] = __builtin_amdgcn_mfma_f32_16x16x32_bf16(fr.s8, bv0, acc[0], 0, 0, 0);
        acc[1] = __builtin_amdgcn_mfma_f32_16x16x32_bf16(fr.s8, bv1, acc[1], 0, 0, 0);
        acc[2] = __builtin_amdgcn_mfma_f32_16x16x32_bf16(fr.s8, bv2, acc[2], 0, 0, 0);
        acc[3] = __builtin_amdgcn_mfma_f32_16x16x32_bf16(fr.s8, bv3, acc[3], 0, 0, 0);
    }
    l += __shfl_xor(l, 16);
    l += __shfl_xor(l, 32);
    const float rl = 1.0f / l;                         // denominator for q = lrow

    if (lgrp == 0) Rl[(size_t)bh * S_LEN + qbase + lrow] = rl;

    // Out[q = lgrp*4+rr][d = vt*16+lrow]; rl is per q=lrow -> redistribute
    float rlo[4];
    #pragma unroll
    for (int rr = 0; rr < 4; ++rr) rlo[rr] = __shfl(rl, lgrp * 4 + rr);

    float* ob = Out + ((size_t)bh * S_LEN + qbase + lgrp * 4) * D_HEAD + lrow;
    #pragma unroll
    for (int vt = 0; vt < 4; ++vt) {
        #pragma unroll
        for (int rr = 0; rr < 4; ++rr) {
            ob[(size_t)rr * D_HEAD + vt * 16] = acc[vt][rr] * rlo[rr];
        }
    }
}

// Kernel B: pure P-writer. Recompute scores for a (16-row q-tile, 1024-col
// k-half), p = exp(s)*rl, store f32x4 direct (cached stores: vmcnt clears at
// L2-ack; L2 pools dirty lines for DRAM). Manual 2-stage K prefetch keeps
// loads ahead of the previous tile's stores in program order.
#define LOADK_B(J, a, b, c, d)                                                  \
    {                                                                           \
        const short* kr0_ = Kp + (size_t)((J) + lrow) * D_HEAD + lgrp * 8;      \
        a = *reinterpret_cast<const short8*>(kr0_);                             \
        b = *reinterpret_cast<const short8*>(kr0_ + 32);                        \
        const short* kr1_ = kr0_ + 16 * D_HEAD;                                 \
        c = *reinterpret_cast<const short8*>(kr1_);                             \
        d = *reinterpret_cast<const short8*>(kr1_ + 32);                        \
    }

#define CSTORE_B(J, k00, k01, k10, k11)                                         \
    {                                                                           \
        f32x4 c0 = {0.f, 0.f, 0.f, 0.f};                                        \
        f32x4 c1 = {0.f, 0.f, 0.f, 0.f};                                        \
        c0 = __builtin_amdgcn_mfma_f32_16x16x32_bf16(k00, q0, c0, 0, 0, 0);     \
        c0 = __builtin_amdgcn_mfma_f32_16x16x32_bf16(k01, q1, c0, 0, 0, 0);     \
        c1 = __builtin_amdgcn_mfma_f32_16x16x32_bf16(k10, q0, c1, 0, 0, 0);     \
        c1 = __builtin_amdgcn_mfma_f32_16x16x32_bf16(k11, q1, c1, 0, 0, 0);     \
        f32x4 p0, p1;                                                           \
        _Pragma("unroll")                                                       \
        for (int rr = 0; rr < 4; ++rr) {                                        \
            p0[rr] = __expf(c0[rr] * scale) * rl;                               \
            p1[rr] = __expf(c1[rr] * scale) * rl;                               \
        }                                                                       \
        *reinterpret_cast<f32x4*>(Prow + (J) + lgrp * 4) = p0;                  \
        *reinterpret_cast<f32x4*>(Prow + (J) + 16 + lgrp * 4) = p1;             \
    }

__launch_bounds__(256, 8)
__global__ void p_writer_kernel(const float* __restrict__ Q,
                                const short* __restrict__ Kb,
                                const float* __restrict__ Rl,
                                float* __restrict__ P) {
    const int lane = threadIdx.x & 63;
    const int w    = threadIdx.x >> 6;
    const int bh   = blockIdx.z;
    const int qbase = blockIdx.x * 64 + w * 16;
    const int kb   = blockIdx.y * (S_LEN / 2);
    const int kend = kb + (S_LEN / 2);
    const int lrow = lane & 15;
    const int lgrp = lane >> 4;
    const float scale = 0.125f;

    short8 q0, q1;
    {
        const float* qr = Q + ((size_t)bh * S_LEN + qbase + lrow) * D_HEAD + lgrp * 8;
        #pragma unroll
        for (int e = 0; e < 8; ++e) q0[e] = f2bf(qr[e]);
        #pragma unroll
        for (int e = 0; e < 8; ++e) q1[e] = f2bf(qr[e + 32]);
    }
    const float rl = Rl[(size_t)bh * S_LEN + qbase + lrow];
    const short* Kp = Kb + (size_t)bh * (S_LEN * D_HEAD);
    float* Prow = P + (size_t)bh * S_LEN * S_LEN + (size_t)(qbase + lrow) * S_LEN;

    short8 A0, A1, A2, A3, B0, B1, B2, B3;
    LOADK_B(kb, A0, A1, A2, A3);
    for (int j0 = kb; j0 < kend; j0 += 64) {
        LOADK_B(j0 + 32, B0, B1, B2, B3);
        CSTORE_B(j0, A0, A1, A2, A3);
        if (j0 + 64 < kend) LOADK_B(j0 + 64, A0, A1, A2, A3);
        CSTORE_B(j0 + 32, B0, B1, B2, B3);
    }
}

extern "C" void kernel_launch(void* const* d_in, const int* in_sizes, int n_in,
                              void* d_out, int out_size, void* d_ws, size_t ws_size,
                              hipStream_t stream) {
    const float* Q = (const float*)d_in[0];
    const float* K = (const float*)d_in[1];
    const float* V = (const float*)d_in[2];
    float* Out = (float*)d_out;
    float* P = Out + (size_t)NELEM;                    // outputs concatenated flat
    short* Kb = (short*)d_ws;                          // 8.4 MB
    short* Vtb = Kb + (size_t)NELEM;                   // 8.4 MB
    float* Rl = (float*)(Vtb + (size_t)NELEM);         // 256 KB (ws >= ~17.1 MB)

    convert_k_kernel<<<NELEM / (256 * 4), 256, 0, stream>>>(K, Kb);
    transpose_v_kernel<<<dim3(S_LEN / 64, NBH), 256, 0, stream>>>(V, Vtb);
    attn_pv_kernel<<<dim3(S_LEN / 64, NBH), 256, 0, stream>>>(Q, Kb, Vtb, Out, Rl);
    p_writer_kernel<<<dim3(S_LEN / 64, 2, NBH), 256, 0, stream>>>(Q, Kb, Rl, P);
}

// Round 6
// 411.035 us; speedup vs baseline: 1.0459x; 1.0459x over previous
//
#include <hip/hip_runtime.h>
#include <hip/hip_bf16.h>
#include <cstdint>
#include <cstddef>

#define S_LEN 2048
#define D_HEAD 64
#define NBH 32                      // B*H = 2*16
#define NELEM 4194304               // NBH * S_LEN * D_HEAD
#define SUPB 1024                   // columns per staged panel phase

typedef __attribute__((ext_vector_type(8))) short short8;
typedef __attribute__((ext_vector_type(4))) float f32x4;

__device__ __forceinline__ short f2bf(float f) {
    union { float f; uint32_t u; } v; v.f = f;
    uint32_t u = v.u + 0x7FFFu + ((v.u >> 16) & 1u);   // RNE, inputs finite
    return (short)(u >> 16);
}

__device__ __forceinline__ uint32_t pkbf(float lo, float hi) {
    return ((uint32_t)(uint16_t)f2bf(hi) << 16) | (uint32_t)(uint16_t)f2bf(lo);
}

// K fp32 -> bf16, same layout
__global__ void convert_k_kernel(const float* __restrict__ K, short* __restrict__ Kb) {
    int i = blockIdx.x * 256 + threadIdx.x;
    float4 x = reinterpret_cast<const float4*>(K)[i];
    short4 y;
    y.x = f2bf(x.x); y.y = f2bf(x.y); y.z = f2bf(x.z); y.w = f2bf(x.w);
    reinterpret_cast<short4*>(Kb)[i] = y;
}

// V fp32 [bh][S][D] -> bf16 transposed [bh][D][S]
__global__ void transpose_v_kernel(const float* __restrict__ V, short* __restrict__ Vtb) {
    __shared__ float tile[64][65];
    const int bh = blockIdx.y;
    const int s0 = blockIdx.x * 64;
    const int d = threadIdx.x & 63;
    const int r = threadIdx.x >> 6;
    const float* vp = V + ((size_t)bh * S_LEN + s0) * D_HEAD;
    #pragma unroll
    for (int i = 0; i < 16; ++i) {
        int s = i * 4 + r;
        tile[s][d] = vp[(size_t)s * D_HEAD + d];
    }
    __syncthreads();
    short* op = Vtb + (size_t)bh * (D_HEAD * S_LEN) + s0;
    #pragma unroll
    for (int i = 0; i < 16; ++i) {
        int dd = i * 4 + r;
        op[(size_t)dd * S_LEN + d] = f2bf(tile[d][dd]);
    }
}

// Kernel A: softmax denominator + PV + Out; writes rl = 1/l per q-row to Rl.
// Swapped QK^T: mfma(A=K, B=Q) -> lane holds scores for q = lane&15 at
// k = (lane>>4)*4 + reg (+16 for the c1 tile). PV A-frag built by in-register
// 4x4 word transpose across lane-groups via 8 ds_bpermute. No LDS, no fences.
__launch_bounds__(256, 4)
__global__ void attn_pv_kernel(const float* __restrict__ Q,
                               const short* __restrict__ Kb,
                               const short* __restrict__ Vtb,
                               float* __restrict__ Out,
                               float* __restrict__ Rl) {
    const int lane = threadIdx.x & 63;
    const int w    = threadIdx.x >> 6;
    const int bh   = blockIdx.y;
    const int qbase = blockIdx.x * 64 + w * 16;
    const int lrow = lane & 15;
    const int lgrp = lane >> 4;
    const float scale = 0.125f;                        // 1/sqrt(64)

    short8 q0, q1;
    {
        const float* qr = Q + ((size_t)bh * S_LEN + qbase + lrow) * D_HEAD + lgrp * 8;
        #pragma unroll
        for (int e = 0; e < 8; ++e) q0[e] = f2bf(qr[e]);
        #pragma unroll
        for (int e = 0; e < 8; ++e) q1[e] = f2bf(qr[e + 32]);
    }

    const short* Kp = Kb + (size_t)bh * (S_LEN * D_HEAD);
    const short* Vp = Vtb + (size_t)bh * (D_HEAD * S_LEN);

    // bpermute source lanes for the 4x4 word transpose (byte addr = lane*4)
    const int srcA = ((lane & 15) + ((lane >> 4) & 1) * 32) << 2;
    const int srcB = srcA + (16 << 2);
    const bool glow = (lgrp < 2);

    float l = 0.f;
    f32x4 acc[4] = {};
    for (int j0 = 0; j0 < S_LEN; j0 += 32) {
        const short* kr0 = Kp + (size_t)(j0 + lrow) * D_HEAD + lgrp * 8;
        const short* kr1 = kr0 + 16 * D_HEAD;
        short8 k00 = *reinterpret_cast<const short8*>(kr0);
        short8 k01 = *reinterpret_cast<const short8*>(kr0 + 32);
        short8 k10 = *reinterpret_cast<const short8*>(kr1);
        short8 k11 = *reinterpret_cast<const short8*>(kr1 + 32);
        short8 bv0 = *reinterpret_cast<const short8*>(Vp + (size_t)(0 * 16 + lrow) * S_LEN + j0 + lgrp * 8);
        short8 bv1 = *reinterpret_cast<const short8*>(Vp + (size_t)(1 * 16 + lrow) * S_LEN + j0 + lgrp * 8);
        short8 bv2 = *reinterpret_cast<const short8*>(Vp + (size_t)(2 * 16 + lrow) * S_LEN + j0 + lgrp * 8);
        short8 bv3 = *reinterpret_cast<const short8*>(Vp + (size_t)(3 * 16 + lrow) * S_LEN + j0 + lgrp * 8);
        f32x4 c0 = {0.f, 0.f, 0.f, 0.f};
        f32x4 c1 = {0.f, 0.f, 0.f, 0.f};
        c0 = __builtin_amdgcn_mfma_f32_16x16x32_bf16(k00, q0, c0, 0, 0, 0);
        c0 = __builtin_amdgcn_mfma_f32_16x16x32_bf16(k01, q1, c0, 0, 0, 0);
        c1 = __builtin_amdgcn_mfma_f32_16x16x32_bf16(k10, q0, c1, 0, 0, 0);
        c1 = __builtin_amdgcn_mfma_f32_16x16x32_bf16(k11, q1, c1, 0, 0, 0);

        float e0[4], e1[4];
        #pragma unroll
        for (int rr = 0; rr < 4; ++rr) {
            e0[rr] = __expf(c0[rr] * scale);
            e1[rr] = __expf(c1[rr] * scale);
            l += e0[rr] + e1[rr];
        }
        int w00 = (int)pkbf(e0[0], e0[1]);
        int w01 = (int)pkbf(e0[2], e0[3]);
        int w10 = (int)pkbf(e1[0], e1[1]);
        int w11 = (int)pkbf(e1[2], e1[3]);
        int t0 = __builtin_amdgcn_ds_bpermute(srcA, w00);
        int t1 = __builtin_amdgcn_ds_bpermute(srcA, w01);
        int t2 = __builtin_amdgcn_ds_bpermute(srcB, w00);
        int t3 = __builtin_amdgcn_ds_bpermute(srcB, w01);
        int u0 = __builtin_amdgcn_ds_bpermute(srcA, w10);
        int u1 = __builtin_amdgcn_ds_bpermute(srcA, w11);
        int u2 = __builtin_amdgcn_ds_bpermute(srcB, w10);
        int u3 = __builtin_amdgcn_ds_bpermute(srcB, w11);
        union { short8 s8; int wd[4]; } fr;
        fr.wd[0] = glow ? t0 : u0;
        fr.wd[1] = glow ? t1 : u1;
        fr.wd[2] = glow ? t2 : u2;
        fr.wd[3] = glow ? t3 : u3;

        acc[0] = __builtin_amdgcn_mfma_f32_16x16x32_bf16(fr.s8, bv0, acc[0], 0, 0, 0);
        acc[1] = __builtin_amdgcn_mfma_f32_16x16x32_bf16(fr.s8, bv1, acc[1], 0, 0, 0);
        acc[2] = __builtin_amdgcn_mfma_f32_16x16x32_bf16(fr.s8, bv2, acc[2], 0, 0, 0);
        acc[3] = __builtin_amdgcn_mfma_f32_16x16x32_bf16(fr.s8, bv3, acc[3], 0, 0, 0);
    }
    l += __shfl_xor(l, 16);
    l += __shfl_xor(l, 32);
    const float rl = 1.0f / l;                         // denominator for q = lrow

    if (lgrp == 0) Rl[(size_t)bh * S_LEN + qbase + lrow] = rl;

    float rlo[4];
    #pragma unroll
    for (int rr = 0; rr < 4; ++rr) rlo[rr] = __shfl(rl, lgrp * 4 + rr);

    float* ob = Out + ((size_t)bh * S_LEN + qbase + lgrp * 4) * D_HEAD + lrow;
    #pragma unroll
    for (int vt = 0; vt < 4; ++vt) {
        #pragma unroll
        for (int rr = 0; rr < 4; ++rr) {
            ob[(size_t)rr * D_HEAD + vt * 16] = acc[vt][rr] * rlo[rr];
        }
    }
}

// Kernel B: pure P-writer, fill-like store stream. One block = 4 waves on a
// single 16-row q-tile. Per phase: waves cooperatively compute a 16x1024
// score panel into 64KB LDS (XOR-swizzled), then 16 drain rounds each write
// ONE ROW's 4KB with all 256 threads fully coalesced, rows ascending.
__launch_bounds__(256, 2)
__global__ void p_writer_kernel(const float* __restrict__ Q,
                                const short* __restrict__ Kb,
                                const float* __restrict__ Rl,
                                float* __restrict__ P) {
    __shared__ __align__(16) float stage[16 * SUPB];   // 64 KB

    const int tid  = threadIdx.x;
    const int lane = tid & 63;
    const int w    = tid >> 6;
    const int bh   = blockIdx.y;
    const int qbase = blockIdx.x * 16;
    const int lrow = lane & 15;
    const int lgrp = lane >> 4;
    const float scale = 0.125f;

    short8 q0, q1;
    {
        const float* qr = Q + ((size_t)bh * S_LEN + qbase + lrow) * D_HEAD + lgrp * 8;
        #pragma unroll
        for (int e = 0; e < 8; ++e) q0[e] = f2bf(qr[e]);
        #pragma unroll
        for (int e = 0; e < 8; ++e) q1[e] = f2bf(qr[e + 32]);
    }
    const float rl = Rl[(size_t)bh * S_LEN + qbase + lrow];
    const short* Kp = Kb + (size_t)bh * (S_LEN * D_HEAD);
    float* Pb = P + (size_t)bh * S_LEN * S_LEN;

    char* stg = (char*)stage;
    const int swz = (lrow & 7) << 4;                   // XOR within 128B groups

    for (int c = 0; c < S_LEN; c += SUPB) {
        // ---- stage phase: wave w computes cols [c+w*256, c+w*256+256) ----
        #pragma unroll
        for (int it = 0; it < 8; ++it) {
            const int jl = w * 256 + it * 32;          // col within panel
            const int j0 = c + jl;                     // global col (= K row)
            const short* kr0 = Kp + (size_t)(j0 + lrow) * D_HEAD + lgrp * 8;
            const short* kr1 = kr0 + 16 * D_HEAD;
            short8 k00 = *reinterpret_cast<const short8*>(kr0);
            short8 k01 = *reinterpret_cast<const short8*>(kr0 + 32);
            short8 k10 = *reinterpret_cast<const short8*>(kr1);
            short8 k11 = *reinterpret_cast<const short8*>(kr1 + 32);
            f32x4 c0 = {0.f, 0.f, 0.f, 0.f};
            f32x4 c1 = {0.f, 0.f, 0.f, 0.f};
            c0 = __builtin_amdgcn_mfma_f32_16x16x32_bf16(k00, q0, c0, 0, 0, 0);
            c0 = __builtin_amdgcn_mfma_f32_16x16x32_bf16(k01, q1, c0, 0, 0, 0);
            c1 = __builtin_amdgcn_mfma_f32_16x16x32_bf16(k10, q0, c1, 0, 0, 0);
            c1 = __builtin_amdgcn_mfma_f32_16x16x32_bf16(k11, q1, c1, 0, 0, 0);
            f32x4 p0, p1;
            #pragma unroll
            for (int rr = 0; rr < 4; ++rr) {
                p0[rr] = __expf(c0[rr] * scale) * rl;
                p1[rr] = __expf(c1[rr] * scale) * rl;
            }
            // value(row=lrow, col_local) at stg[row*4096 + (col_local*4 ^ swz)]
            *(f32x4*)(stg + (lrow * 4096 + (((jl + lgrp * 4) << 2) ^ swz))) = p0;
            *(f32x4*)(stg + (lrow * 4096 + (((jl + 16 + lgrp * 4) << 2) ^ swz))) = p1;
        }
        __syncthreads();
        // ---- drain phase: 16 rounds, one row per round, 4KB coalesced ----
        #pragma unroll
        for (int r = 0; r < 16; ++r) {
            const int off = (tid * 16) ^ ((r & 7) << 4);   // un-swizzle
            f32x4 v = *(const f32x4*)(stg + r * 4096 + tid * 16);
            // value at plain LDS slot t*16 is col*4 = (t*16 ^ swz(r))
            *(f32x4*)((char*)(Pb + (size_t)(qbase + r) * S_LEN + c) + off) = v;
        }
        __syncthreads();
    }
}

extern "C" void kernel_launch(void* const* d_in, const int* in_sizes, int n_in,
                              void* d_out, int out_size, void* d_ws, size_t ws_size,
                              hipStream_t stream) {
    const float* Q = (const float*)d_in[0];
    const float* K = (const float*)d_in[1];
    const float* V = (const float*)d_in[2];
    float* Out = (float*)d_out;
    float* P = Out + (size_t)NELEM;                    // outputs concatenated flat
    short* Kb = (short*)d_ws;                          // 8.4 MB
    short* Vtb = Kb + (size_t)NELEM;                   // 8.4 MB
    float* Rl = (float*)(Vtb + (size_t)NELEM);         // 256 KB (ws >= ~17.1 MB)

    convert_k_kernel<<<NELEM / (256 * 4), 256, 0, stream>>>(K, Kb);
    transpose_v_kernel<<<dim3(S_LEN / 64, NBH), 256, 0, stream>>>(V, Vtb);
    attn_pv_kernel<<<dim3(S_LEN / 64, NBH), 256, 0, stream>>>(Q, Kb, Vtb, Out, Rl);
    p_writer_kernel<<<dim3(S_LEN / 16, NBH), 256, 0, stream>>>(Q, Kb, Rl, P);
}